// Round 5
// baseline (26.299 us; speedup 1.0000x reference)
//
#include <hip/hip_runtime.h>
#include <hip/hip_bf16.h>
#include <math.h>

#define NUM_WIRES 512

typedef float f4 __attribute__((ext_vector_type(4)));

__device__ __forceinline__ f4 ntload(const f4* p) {
    return __builtin_nontemporal_load(p);
}

__device__ __forceinline__ float dot8(f4 a, f4 b, f4 ca, f4 cb) {
    return a[0]*ca[0] + a[1]*ca[1] + a[2]*ca[2] + a[3]*ca[3]
         + b[0]*cb[0] + b[1]*cb[1] + b[2]*cb[2] + b[3]*cb[3];
}

// out[b] = sum_j coeff[j]*x[b,j] + bias
//   coeff[j] = head_w[j] * 2*exp(-squeeze2[j])*exp(-squeeze[j])*cos(phase[j])
//   bias     = head_b[0] + sum_j head_w[j] * 2*exp(-squeeze2[j])*disp[j]
// (sqrt(2*HBAR)=2 exactly; kerr is dead.)
// Barrier-free preamble; 4 rows / 8 float4 loads in flight per iteration.
// NOTE: 8-row-upfront variant (R4) spilled under the 128-VGPR cap and
// diverged post-timing — this spill-free shape is the proven optimum.
__global__ __launch_bounds__(256, 4) void fused_dot_kernel(
        const float* __restrict__ x,
        const float* __restrict__ squeeze,
        const float* __restrict__ phase,
        const float* __restrict__ disp,
        const float* __restrict__ squeeze2,
        const float* __restrict__ head_w,
        const float* __restrict__ head_b,
        float* __restrict__ out, int rows) {
    const int t = threadIdx.x;
    const int lane = t & 63;
    const int wave = t >> 6;
    const int waveId = blockIdx.x * 4 + wave;
    const int base = waveId * 8;               // 8 rows per wave
    if (base >= rows) return;

    // ---- per-lane coeff fragment (columns lane*4..+3 and 256+lane*4..+3) ----
    const f4 sqa = ((const f4*)squeeze )[lane], sqb = ((const f4*)squeeze )[64 + lane];
    const f4 pha = ((const f4*)phase   )[lane], phb = ((const f4*)phase   )[64 + lane];
    const f4 dia = ((const f4*)disp    )[lane], dib = ((const f4*)disp    )[64 + lane];
    const f4 s2a = ((const f4*)squeeze2)[lane], s2b = ((const f4*)squeeze2)[64 + lane];
    const f4 wa  = ((const f4*)head_w  )[lane], wb  = ((const f4*)head_w  )[64 + lane];

    f4 c0, c1;
    float part = 0.0f;
    #pragma unroll
    for (int k = 0; k < 4; ++k) {
        const float e2a = expf(-s2a[k]);
        const float e2b = expf(-s2b[k]);
        c0[k] = wa[k] * 2.0f * e2a * expf(-sqa[k]) * cosf(pha[k]);
        c1[k] = wb[k] * 2.0f * e2b * expf(-sqb[k]) * cosf(phb[k]);
        part += wa[k] * 2.0f * e2a * dia[k] + wb[k] * 2.0f * e2b * dib[k];
    }
    #pragma unroll
    for (int off = 32; off >= 1; off >>= 1)
        part += __shfl_xor(part, off, 64);
    const float bias = part + head_b[0];

    // ---- stream 8 rows, 4 per iteration (8 float4 loads in flight) ----
    const f4* xb = (const f4*)(x + (size_t)base * NUM_WIRES);   // 128 f4 per row
    #pragma unroll
    for (int i = 0; i < 2; ++i) {
        const int r0 = base + i * 4;
        const f4* p = xb + (size_t)i * 4 * 128;
        const f4 a0 = ntload(p +        lane), b0 = ntload(p +  64 + lane);
        const f4 a1 = ntload(p + 128 +  lane), b1 = ntload(p + 192 + lane);
        const f4 a2 = ntload(p + 256 +  lane), b2 = ntload(p + 320 + lane);
        const f4 a3 = ntload(p + 384 +  lane), b3 = ntload(p + 448 + lane);

        float s0 = dot8(a0, b0, c0, c1);
        float s1 = dot8(a1, b1, c0, c1);
        float s2 = dot8(a2, b2, c0, c1);
        float s3 = dot8(a3, b3, c0, c1);

        // paired butterfly: 4 rows in 10 shfls
        s0 += __shfl_xor(s0, 32, 64);
        s1 += __shfl_xor(s1, 32, 64);
        s2 += __shfl_xor(s2, 32, 64);
        s3 += __shfl_xor(s3, 32, 64);
        float u0 = (lane & 32) ? s1 : s0;   // halves: row0 | row1
        float u1 = (lane & 32) ? s3 : s2;   // halves: row2 | row3
        u0 += __shfl_xor(u0, 16, 64);
        u1 += __shfl_xor(u1, 16, 64);
        float v = (lane & 16) ? u1 : u0;    // 16-groups: row0|row2|row1|row3
        v += __shfl_xor(v, 8, 64);
        v += __shfl_xor(v, 4, 64);
        v += __shfl_xor(v, 2, 64);
        v += __shfl_xor(v, 1, 64);

        if ((lane & 15) == 0) {
            const int roff = ((lane >> 4) & 1) * 2 + (lane >> 5);  // 0,2,1,3
            const int r = r0 + roff;
            if (r < rows) out[r] = v + bias;
        }
    }
}

extern "C" void kernel_launch(void* const* d_in, const int* in_sizes, int n_in,
                              void* d_out, int out_size, void* d_ws, size_t ws_size,
                              hipStream_t stream) {
    const float* state_batch = (const float*)d_in[0];  // (65536, 512)
    const float* squeeze     = (const float*)d_in[1];
    const float* phase       = (const float*)d_in[2];
    const float* disp        = (const float*)d_in[3];
    const float* squeeze2    = (const float*)d_in[4];
    // d_in[5] = kerr — unused by the reference output
    const float* head_w      = (const float*)d_in[6];
    const float* head_b      = (const float*)d_in[7];
    float* out = (float*)d_out;

    fused_dot_kernel<<<2048, 256, 0, stream>>>(state_batch, squeeze, phase, disp,
                                               squeeze2, head_w, head_b, out, out_size);
}